// Round 1
// 352.892 us; speedup vs baseline: 1.0821x; 1.0821x over previous
//
#include <hip/hip_runtime.h>
#include <hip/hip_bf16.h>

// ---------------- constants (problem shape) ----------------
// B=2, S=2048, H=2048, NH=16, LD=512, HD=128
#define PB   2
#define PS   2048
#define PH   2048
#define PNH  16
#define PLD  512
#define PHD  128
#define PM   (PB * PS)          // 4096 rows in all GEMMs
#define PNCAT 3072              // merged down-proj width: 2048 q + 512 klat + 512 vlat
#define ATT_SCALE 0.08838834764831845f  // 1/sqrt(128)
#define ATT_MOFF 4.0f

typedef __attribute__((ext_vector_type(8))) short bf16x8;
typedef __attribute__((ext_vector_type(4))) float f32x4;

__device__ __forceinline__ unsigned short f2bf(float f) {
    unsigned int u = __float_as_uint(f);
    u += 0x7FFFu + ((u >> 16) & 1u);   // RNE
    return (unsigned short)(u >> 16);
}

// async global->LDS, 16 B per lane; LDS dest = wave-uniform base + lane*16
__device__ __forceinline__ void gl_lds16(const unsigned short* g, unsigned short* l) {
    __builtin_amdgcn_global_load_lds(
        (const __attribute__((address_space(1))) unsigned int*)g,
        (__attribute__((address_space(3))) unsigned int*)l, 16, 0, 0);
}

#define VMCNT(n)   asm volatile("s_waitcnt vmcnt(" #n ")" ::: "memory")
#define LGKM0()    asm volatile("s_waitcnt lgkmcnt(0)" ::: "memory")
#define MEMFENCE() asm volatile("" ::: "memory")

// ---------------- cast fp32 -> bf16 (elementwise, 4/thread) ----------------
__global__ __launch_bounds__(256) void cast_f32_bf16_kernel(
    const float* __restrict__ in, unsigned short* __restrict__ out, int n)
{
    int i = (blockIdx.x * 256 + threadIdx.x) * 4;
    if (i >= n) return;
    float4 f = *(const float4*)(in + i);
    unsigned int a = (unsigned int)f2bf(f.x) | ((unsigned int)f2bf(f.y) << 16);
    unsigned int b = (unsigned int)f2bf(f.z) | ((unsigned int)f2bf(f.w) << 16);
    *(uint2*)(out + i) = make_uint2(a, b);
}

// ---------------- transpose + cast: in fp32 [R][C] -> out bf16 [C][R] ----------------
__global__ __launch_bounds__(256) void transpose_cast_kernel(
    const float* __restrict__ in, unsigned short* __restrict__ out, int R, int C)
{
    __shared__ float tile[32][33];
    int tx = threadIdx.x, ty = threadIdx.y;
    int r0 = blockIdx.y * 32, c0 = blockIdx.x * 32;
#pragma unroll
    for (int i = 0; i < 32; i += 8)
        tile[ty + i][tx] = in[(size_t)(r0 + ty + i) * C + (c0 + tx)];
    __syncthreads();
#pragma unroll
    for (int i = 0; i < 32; i += 8)
        out[(size_t)(c0 + ty + i) * R + (r0 + tx)] = f2bf(tile[tx][ty + i]);
}

// ---------------- 8-phase 256-wide bf16 MFMA GEMM (T2+T3+T4+T5+T1) ----------------
// BM in {128,256}, BN fixed 256. 512 threads = 8 waves (2M x 4N).
// LDS: dbuf x (A BM*64 + B 256*64) bf16, XOR-swizzled (byte ^= (row&7)<<4) via
// pre-swizzled global source (linear global_load_lds dest) + swizzled ds_read.
// K-tile BK=64, 4 phases/K-tile, counted vmcnt(2) once per tile (0 in epilogue).
// EPI: 0 = bf16 row-major, 1 = fp32 row-major, 2 = K-swizzled, 3 = V-swizzled.
template<int BM, int EPI, bool HAS_BIAS>
__global__ __launch_bounds__(512, 2) void gemm8p_kernel(
    const unsigned short* __restrict__ A, int lda,
    const unsigned short* __restrict__ BT,
    const float* __restrict__ bias, int nbias,
    void* __restrict__ Cout, int ldc, int K)
{
    constexpr int AH  = BM / 128;   // A half-tiles per K-tile (1 or 2)
    constexpr int MR  = BM / 32;    // per-wave m fragment reps (4 or 8)
    constexpr int MH  = MR / 2;     // m reps per phase
    constexpr int ASZ = BM * 64;    // elements per A K-tile buffer
    __shared__ __align__(16) unsigned short lds[2 * ASZ + 32768];  // 96 or 128 KiB

    const int tid  = threadIdx.x;
    const int wave = tid >> 6, lane = tid & 63;
    const int wm = wave >> 2, wn = wave & 3;
    const int quad = lane >> 4, l15 = lane & 15;
    const int sw = l15 & 7;         // read-side XOR (== row&7 of every frag row)

    // T1: bijective XCD-aware swizzle of the linear workgroup id
    const int gx  = gridDim.x;
    const int nwg = gx * gridDim.y;
    int wg = blockIdx.y * gx + blockIdx.x;
    if (!(nwg & 7)) wg = (wg & 7) * (nwg >> 3) + (wg >> 3);
    const int bm = (wg / gx) * BM, bn = (wg % gx) * 256;

    const int nt = K >> 6;

    // staging: thread tid covers (row = tid/8 [+64], 16B-slot p = tid&7) of a
    // 128x64 half-tile; LDS dest linear => fetch pre-swizzled global column.
    const int srow = tid >> 3;
    const int scol = ((tid & 7) ^ (srow & 7)) << 3;  // elements
    const unsigned short* Ag = A  + (size_t)(bm + srow) * lda + scol;
    const unsigned short* Bg = BT + (size_t)(bn + srow) * K   + scol;
    unsigned short* const ldsA = &lds[wave * 512];
    unsigned short* const ldsB = &lds[2 * ASZ + wave * 512];

    auto stA = [&](int kt, int h, int b) {
        const unsigned short* g = Ag + (size_t)(h * 128) * lda + kt * 64;
        unsigned short* l = ldsA + b * ASZ + h * 8192;
        gl_lds16(g, l);
        gl_lds16(g + (size_t)64 * lda, l + 4096);
    };
    auto stB = [&](int kt, int h, int b) {
        const unsigned short* g = Bg + (size_t)(h * 128) * K + kt * 64;
        unsigned short* l = ldsB + b * 16384 + h * 8192;
        gl_lds16(g, l);
        gl_lds16(g + (size_t)64 * K, l + 4096);
    };

    // fragment reads: logical (row, slot s=ks*4+quad) -> physical slot s^ (row&7)
    auto ldA = [&](int b, int m, int ks) -> bf16x8 {
        int ra = wm * (BM / 2) + m * 16 + l15;
        return *(const bf16x8*)&lds[b * ASZ + (ra >> 7) * 8192 + (ra & 127) * 64
                                    + (((ks * 4 + quad) ^ sw) << 3)];
    };
    auto ldB = [&](int b, int j, int ks) -> bf16x8 {
        int rb = wn * 64 + j * 16 + l15;
        return *(const bf16x8*)&lds[2 * ASZ + b * 16384 + (rb >> 7) * 8192 + (rb & 127) * 64
                                    + (((ks * 4 + quad) ^ sw) << 3)];
    };

    f32x4 acc[MR][4] = {};
    bf16x8 af[MH][2], bl[2][2], bh[2][2];

    // ---- prologue: tile0 fully + A0(1); leave A0(1) in flight ----
    stA(0, 0, 0);
    if constexpr (AH == 2) stA(0, 1, 0);
    stB(0, 0, 0);
    stB(0, 1, 0);
    if (nt > 1) { stA(1, 0, 1); VMCNT(2); } else { VMCNT(0); }
    __builtin_amdgcn_s_barrier();
    MEMFENCE();

    // issue map (steady state, all races checked vs per-phase readers):
    //   p1: A1(t+1) [BM=256] / B0(t+1) [BM=128]   p2: B1(t+1)
    //   p3: B0(t+1) [BM=256] / -   [BM=128]       p4: A0(t+2), wait vmcnt(2)
    for (int t = 0; t < nt; ++t) {
        const int b = t & 1, nb = b ^ 1;
        const bool s1 = (t + 1 < nt), s2 = (t + 2 < nt);

        // ---------- phase 1: A(mh0) + B(lo) frags ----------
#pragma unroll
        for (int m = 0; m < MH; ++m)
#pragma unroll
            for (int ks = 0; ks < 2; ++ks) af[m][ks] = ldA(b, m, ks);
#pragma unroll
        for (int j = 0; j < 2; ++j)
#pragma unroll
            for (int ks = 0; ks < 2; ++ks) bl[j][ks] = ldB(b, j, ks);
        if (s1) { if constexpr (AH == 2) stA(t + 1, 1, nb); else stB(t + 1, 0, nb); }
        __builtin_amdgcn_s_barrier();
        LGKM0();
        __builtin_amdgcn_sched_barrier(0);
        __builtin_amdgcn_s_setprio(1);
#pragma unroll
        for (int m = 0; m < MH; ++m)
#pragma unroll
            for (int j = 0; j < 2; ++j)
#pragma unroll
                for (int ks = 0; ks < 2; ++ks)
                    acc[m][j] = __builtin_amdgcn_mfma_f32_16x16x32_bf16(af[m][ks], bl[j][ks], acc[m][j], 0, 0, 0);
        __builtin_amdgcn_s_setprio(0);
        __builtin_amdgcn_s_barrier();

        // ---------- phase 2: B(hi) frags, reuse A(mh0) ----------
#pragma unroll
        for (int j = 0; j < 2; ++j)
#pragma unroll
            for (int ks = 0; ks < 2; ++ks) bh[j][ks] = ldB(b, 2 + j, ks);
        if (s1) stB(t + 1, 1, nb);
        __builtin_amdgcn_s_barrier();
        LGKM0();
        __builtin_amdgcn_sched_barrier(0);
        __builtin_amdgcn_s_setprio(1);
#pragma unroll
        for (int m = 0; m < MH; ++m)
#pragma unroll
            for (int j = 0; j < 2; ++j)
#pragma unroll
                for (int ks = 0; ks < 2; ++ks)
                    acc[m][2 + j] = __builtin_amdgcn_mfma_f32_16x16x32_bf16(af[m][ks], bh[j][ks], acc[m][2 + j], 0, 0, 0);
        __builtin_amdgcn_s_setprio(0);
        __builtin_amdgcn_s_barrier();

        // ---------- phase 3: A(mh1) frags, reuse B(hi) ----------
#pragma unroll
        for (int m = 0; m < MH; ++m)
#pragma unroll
            for (int ks = 0; ks < 2; ++ks) af[m][ks] = ldA(b, MH + m, ks);
        if (s1) { if constexpr (AH == 2) stB(t + 1, 0, nb); }
        __builtin_amdgcn_s_barrier();
        LGKM0();
        __builtin_amdgcn_sched_barrier(0);
        __builtin_amdgcn_s_setprio(1);
#pragma unroll
        for (int m = 0; m < MH; ++m)
#pragma unroll
            for (int j = 0; j < 2; ++j)
#pragma unroll
                for (int ks = 0; ks < 2; ++ks)
                    acc[MH + m][2 + j] = __builtin_amdgcn_mfma_f32_16x16x32_bf16(af[m][ks], bh[j][ks], acc[MH + m][2 + j], 0, 0, 0);
        __builtin_amdgcn_s_setprio(0);
        __builtin_amdgcn_s_barrier();

        // ---------- phase 4: reload B(lo), reuse A(mh1); tile-boundary wait ----------
#pragma unroll
        for (int j = 0; j < 2; ++j)
#pragma unroll
            for (int ks = 0; ks < 2; ++ks) bl[j][ks] = ldB(b, j, ks);
        if (s2) stA(t + 2, 0, b);
        __builtin_amdgcn_s_barrier();
        LGKM0();
        __builtin_amdgcn_sched_barrier(0);
        __builtin_amdgcn_s_setprio(1);
#pragma unroll
        for (int m = 0; m < MH; ++m)
#pragma unroll
            for (int j = 0; j < 2; ++j)
#pragma unroll
                for (int ks = 0; ks < 2; ++ks)
                    acc[MH + m][j] = __builtin_amdgcn_mfma_f32_16x16x32_bf16(af[m][ks], bl[j][ks], acc[MH + m][j], 0, 0, 0);
        __builtin_amdgcn_s_setprio(0);
        if (s2) { VMCNT(2); } else { VMCNT(0); }   // next tile ready; A0(t+2) stays in flight
        __builtin_amdgcn_s_barrier();
        MEMFENCE();  // no LDS read may hoist above this tile boundary
    }

    // ---------- epilogue ----------
#pragma unroll
    for (int m = 0; m < MR; ++m)
#pragma unroll
        for (int j = 0; j < 4; ++j)
#pragma unroll
            for (int r = 0; r < 4; ++r) {
                int row = bm + wm * (BM / 2) + m * 16 + quad * 4 + r;
                int col = bn + wn * 64 + j * 16 + l15;
                float val = acc[m][j][r];
                if (HAS_BIAS && col < nbias) val += bias[col];
                if (EPI == 2) {
                    // K frag layout, head bh=b*16+h: [tile s/64][dim-chunk d/8][key s%64][d%8]
                    int bb = row >> 11, s = row & 2047, hh = col >> 7, d = col & 127;
                    size_t idx = ((size_t)((bb << 4) + hh) << 18) + ((size_t)(s >> 6) << 13)
                               + ((d >> 3) << 9) + ((s & 63) << 3) + (d & 7);
                    ((unsigned short*)Cout)[idx] = f2bf(val);
                } else if (EPI == 3) {
                    // V frag layout, head bh: [tile s/64][key-chunk (s%64)/8][dim d(128)][s%8]
                    int bb = row >> 11, s = row & 2047, hh = col >> 7, d = col & 127;
                    size_t idx = ((size_t)((bb << 4) + hh) << 18) + ((size_t)(s >> 6) << 13)
                               + (((s >> 3) & 7) << 10) + (d << 3) + (s & 7);
                    ((unsigned short*)Cout)[idx] = f2bf(val);
                } else if (EPI == 1) {
                    ((float*)Cout)[(size_t)row * ldc + col] = val;
                } else {
                    ((unsigned short*)Cout)[(size_t)row * ldc + col] = f2bf(val);
                }
            }
}

// ---------------- MFMA flash attention: fixed-offset softmax, MFMA row-sum ----------------
// grid 1024 blocks (32 bh x 32 q-tiles of 64), 256 threads (4 waves x 16 queries).
__global__ __launch_bounds__(256) void flash_attn_mfma_kernel(
    const unsigned short* __restrict__ q,
    const unsigned short* __restrict__ kswz,
    const unsigned short* __restrict__ vswz,
    unsigned short* __restrict__ o)
{
    __shared__ __align__(16) unsigned short Kl[2][8192];    // 32 KB dbuf [chunk16][key64][8]
    __shared__ __align__(16) unsigned short Vl[8192];       // 16 KB [chunk8][dim128][8]
    __shared__ __align__(16) unsigned short Ps[4][16][72];  // wave-private P

    const int tid  = threadIdx.x;
    const int wave = tid >> 6;
    const int lane = tid & 63;
    const int quad = lane >> 4, l15 = lane & 15;

    const int bid = blockIdx.x;
    const int qt = 31 - (bid >> 5);     // longest tiles dispatch first
    const int bh = bid & 31;            // head pinned to one XCD-L2
    const int b  = bh >> 4, h = bh & 15;
    const int q0 = qt * 64;

    const unsigned short* qbase = q + (size_t)(b * PS + q0) * PNCAT + h * PHD;
    const unsigned short* kbase = kswz + ((size_t)bh << 18);
    const unsigned short* vbase = vswz + ((size_t)bh << 18);

    auto stageK = [&](int it, int buf) {
        const unsigned short* kt = kbase + ((size_t)it << 13);
#pragma unroll
        for (int j = 0; j < 4; ++j)
            gl_lds16(kt + (wave * 4 + j) * 512 + lane * 8, &Kl[buf][(wave * 4 + j) * 512]);
    };
    auto stageV = [&](int it) {
        const unsigned short* vt = vbase + ((size_t)it << 13);
#pragma unroll
        for (int j = 0; j < 4; ++j)
            gl_lds16(vt + (wave * 4 + j) * 512 + lane * 8, &Vl[(wave * 4 + j) * 512]);
    };

    // Q A-frags: registers for whole kernel
    bf16x8 aq[4];
#pragma unroll
    for (int kk = 0; kk < 4; ++kk)
        aq[kk] = *(const bf16x8*)(qbase + (size_t)(wave * 16 + l15) * PNCAT + kk * 32 + quad * 8);

    bf16x8 vones;
#pragma unroll
    for (int j = 0; j < 8; ++j) vones[j] = (short)0x3F80;

    f32x4 oacc[8] = {};
    f32x4 lacc = {};

    stageK(0, 0);   // prologue prefetch

    for (int it = 0; it <= qt; ++it) {
        const int cur = it & 1;
        __syncthreads();   // B1: K[it] visible; prior-iter Vl readers done
        stageV(it);
        if (it < qt) stageK(it + 1, cur ^ 1);

        // ---- S = Q K^T on Kl[cur] ----
        f32x4 sacc[4] = {};
#pragma unroll
        for (int kk = 0; kk < 4; ++kk)
#pragma unroll
            for (int n = 0; n < 4; ++n) {
                bf16x8 bk = *(const bf16x8*)&Kl[cur][((kk * 4 + quad) * 64 + n * 16 + l15) * 8];
                sacc[n] = __builtin_amdgcn_mfma_f32_16x16x32_bf16(aq[kk], bk, sacc[n], 0, 0, 0);
            }

        // ---- P = exp(s*scale - MOFF); causal zero on diagonal tile; write to LDS ----
        const bool diag = (it == qt);
#pragma unroll
        for (int n = 0; n < 4; ++n)
#pragma unroll
            for (int r = 0; r < 4; ++r) {
                float p = __expf(fmaf(sacc[n][r], ATT_SCALE, -ATT_MOFF));
                if (diag && (n * 16 + l15 > wave * 16 + quad * 4 + r)) p = 0.0f;
                Ps[wave][quad * 4 + r][n * 16 + l15] = f2bf(p);  // wave-private
            }

        __syncthreads();   // B2: V[it] visible (loads had QK+exp in flight)

        // ---- O += P V ; l += P 1 (row-sum via ones MFMA) ----
#pragma unroll
        for (int kk = 0; kk < 2; ++kk) {
            bf16x8 ap = *(const bf16x8*)&Ps[wave][l15][kk * 32 + quad * 8];
            lacc = __builtin_amdgcn_mfma_f32_16x16x32_bf16(ap, vones, lacc, 0, 0, 0);
#pragma unroll
            for (int n = 0; n < 8; ++n) {
                bf16x8 bv = *(const bf16x8*)&Vl[((kk * 4 + quad) * 128 + n * 16 + l15) * 8];
                oacc[n] = __builtin_amdgcn_mfma_f32_16x16x32_bf16(ap, bv, oacc[n], 0, 0, 0);
            }
        }
    }

    // ---- epilogue: normalize by l, store bf16 ----
    float inv[4];
#pragma unroll
    for (int r = 0; r < 4; ++r) inv[r] = 1.0f / lacc[r];
#pragma unroll
    for (int n = 0; n < 8; ++n)
#pragma unroll
        for (int r = 0; r < 4; ++r) {
            int row = q0 + wave * 16 + quad * 4 + r;
            int col = h * PHD + n * 16 + l15;
            o[(size_t)(b * PS + row) * PH + col] = f2bf(oacc[n][r] * inv[r]);
        }
}

// ---------------- host launcher ----------------
extern "C" void kernel_launch(void* const* d_in, const int* in_sizes, int n_in,
                              void* d_out, int out_size, void* d_ws, size_t ws_size,
                              hipStream_t stream)
{
    const float* x      = (const float*)d_in[0];
    const float* wq     = (const float*)d_in[1];
    const float* bq     = (const float*)d_in[2];
    const float* wk_lat = (const float*)d_in[3];
    const float* wv_lat = (const float*)d_in[4];
    const float* wk     = (const float*)d_in[5];
    const float* wv     = (const float*)d_in[6];
    const float* wo     = (const float*)d_in[7];
    const float* bo     = (const float*)d_in[8];
    float* out = (float*)d_out;

    char* ws = (char*)d_ws;
    size_t off = 0;
    auto alloc = [&](size_t bytes) -> void* {
        void* p = ws + off;
        off += (bytes + 255) & ~(size_t)255;
        return p;
    };
    unsigned short* xb    = (unsigned short*)alloc((size_t)PM * PH * 2);       // 16 MB
    unsigned short* wcatT = (unsigned short*)alloc((size_t)PNCAT * PH * 2);    // 12 MB
    unsigned short* wkT   = (unsigned short*)alloc((size_t)PH * PLD * 2);      // 2 MB
    unsigned short* wvT   = (unsigned short*)alloc((size_t)PH * PLD * 2);      // 2 MB
    unsigned short* woT   = (unsigned short*)alloc((size_t)PH * PH * 2);       // 8 MB
    unsigned short* cat   = (unsigned short*)alloc((size_t)PM * PNCAT * 2);    // 24 MB
    unsigned short* kswz  = (unsigned short*)alloc((size_t)PM * PH * 2);       // 16 MB
    unsigned short* attn  = (unsigned short*)alloc((size_t)PM * PH * 2);       // 16 MB
    // vswz aliases xb: xb dead after the merged down-proj reads it.
    unsigned short* vswz  = xb;

    unsigned short* wqT    = wcatT;                                  // rows 0..2047
    unsigned short* wkLatT = wcatT + (size_t)PH * PH;                // rows 2048..2559
    unsigned short* wvLatT = wcatT + (size_t)(PH + PLD) * PH;        // rows 2560..3071

    dim3 tb(32, 8);

    // 1. cast x -> bf16
    cast_f32_bf16_kernel<<<(PM * PH) / 4 / 256, 256, 0, stream>>>(x, xb, PM * PH);
    // 2. transpose weights -> bf16 B^T layouts
    transpose_cast_kernel<<<dim3(PH / 32,  PH / 32),  tb, 0, stream>>>(wq,     wqT,    PH,  PH);
    transpose_cast_kernel<<<dim3(PLD / 32, PH / 32),  tb, 0, stream>>>(wk_lat, wkLatT, PH,  PLD);
    transpose_cast_kernel<<<dim3(PLD / 32, PH / 32),  tb, 0, stream>>>(wv_lat, wvLatT, PH,  PLD);
    transpose_cast_kernel<<<dim3(PH / 32,  PLD / 32), tb, 0, stream>>>(wk,     wkT,    PLD, PH);
    transpose_cast_kernel<<<dim3(PH / 32,  PLD / 32), tb, 0, stream>>>(wv,     wvT,    PLD, PH);
    transpose_cast_kernel<<<dim3(PH / 32,  PH / 32),  tb, 0, stream>>>(wo,     woT,    PH,  PH);

    // 3. merged down-projection: cat[M][3072] = xb @ [wq | wk_lat | wv_lat] (+bq on first 2048)
    //    256x256 tile -> grid 12x16 = 192 WGs
    gemm8p_kernel<256, 0, true><<<dim3(PNCAT / 256, PM / 256), 512, 0, stream>>>(
        xb, PH, wcatT, bq, PH, cat, PNCAT, PH);

    // 4. up-projections straight into MFMA-fragment-swizzled K / V
    //    128x256 tile -> grid 8x32 = 256 WGs (100% of CUs)
    gemm8p_kernel<128, 2, false><<<dim3(PH / 256, PM / 128), 512, 0, stream>>>(
        cat + PH, PNCAT, wkT, nullptr, 0, kswz, 0, PLD);
    gemm8p_kernel<128, 3, false><<<dim3(PH / 256, PM / 128), 512, 0, stream>>>(
        cat + PH + PLD, PNCAT, wvT, nullptr, 0, vswz, 0, PLD);

    // 5. causal MFMA flash attention
    flash_attn_mfma_kernel<<<PB * PNH * (PS / 64), 256, 0, stream>>>(cat, kswz, vswz, attn);

    // 6. output projection (fp32 out + bo), 128x256 tile -> 256 WGs
    gemm8p_kernel<128, 1, true><<<dim3(PH / 256, PM / 128), 512, 0, stream>>>(
        attn, PH, woT, bo, PH, out, PH, PH);
}

// Round 2
// 352.562 us; speedup vs baseline: 1.0831x; 1.0009x over previous
//
#include <hip/hip_runtime.h>
#include <hip/hip_bf16.h>

// ---------------- constants (problem shape) ----------------
// B=2, S=2048, H=2048, NH=16, LD=512, HD=128
#define PB   2
#define PS   2048
#define PH   2048
#define PNH  16
#define PLD  512
#define PHD  128
#define PM   (PB * PS)          // 4096 rows in all GEMMs
#define PNCAT 3072              // merged down-proj width: 2048 q + 512 klat + 512 vlat
#define ATT_SCALE 0.08838834764831845f  // 1/sqrt(128)
#define ATT_MOFF 4.0f

typedef __attribute__((ext_vector_type(8))) short bf16x8;
typedef __attribute__((ext_vector_type(4))) float f32x4;

__device__ __forceinline__ unsigned short f2bf(float f) {
    unsigned int u = __float_as_uint(f);
    u += 0x7FFFu + ((u >> 16) & 1u);   // RNE
    return (unsigned short)(u >> 16);
}

// async global->LDS, 16 B per lane; LDS dest = wave-uniform base + lane*16
__device__ __forceinline__ void gl_lds16(const unsigned short* g, unsigned short* l) {
    __builtin_amdgcn_global_load_lds(
        (const __attribute__((address_space(1))) unsigned int*)g,
        (__attribute__((address_space(3))) unsigned int*)l, 16, 0, 0);
}

#define VMCNT(n)   asm volatile("s_waitcnt vmcnt(" #n ")" ::: "memory")
#define LGKM0()    asm volatile("s_waitcnt lgkmcnt(0)" ::: "memory")
#define MEMFENCE() asm volatile("" ::: "memory")

// ---------------- cast fp32 -> bf16 (elementwise, 4/thread) ----------------
__global__ __launch_bounds__(256) void cast_f32_bf16_kernel(
    const float* __restrict__ in, unsigned short* __restrict__ out, int n)
{
    int i = (blockIdx.x * 256 + threadIdx.x) * 4;
    if (i >= n) return;
    float4 f = *(const float4*)(in + i);
    unsigned int a = (unsigned int)f2bf(f.x) | ((unsigned int)f2bf(f.y) << 16);
    unsigned int b = (unsigned int)f2bf(f.z) | ((unsigned int)f2bf(f.w) << 16);
    *(uint2*)(out + i) = make_uint2(a, b);
}

// ---------------- transpose + cast: in fp32 [R][C] -> out bf16 [C][R] ----------------
__global__ __launch_bounds__(256) void transpose_cast_kernel(
    const float* __restrict__ in, unsigned short* __restrict__ out, int R, int C)
{
    __shared__ float tile[32][33];
    int tx = threadIdx.x, ty = threadIdx.y;
    int r0 = blockIdx.y * 32, c0 = blockIdx.x * 32;
#pragma unroll
    for (int i = 0; i < 32; i += 8)
        tile[ty + i][tx] = in[(size_t)(r0 + ty + i) * C + (c0 + tx)];
    __syncthreads();
#pragma unroll
    for (int i = 0; i < 32; i += 8)
        out[(size_t)(c0 + ty + i) * R + (r0 + tx)] = f2bf(tile[tx][ty + i]);
}

// ---------------- 8-phase 256-wide bf16 MFMA GEMM, deep-pipelined ----------------
// BM in {128,256}, BN fixed 256. 512 threads = 8 waves, INTERLEAVED mapping:
//   A row  = m*32 + wm*16 + l15   (fragment index m selects the 64-row stage unit
//   B row  = j*64 + wn*16 + l15    for ALL waves -> per-unit single-phase liveness)
// Per tile t (4 phases, quadrants (Alo,Blo),(Alo,Bhi),(Ahi,Bhi),(Ahi,Blo)):
//   phi1 stages Blo(t+1); phi3 stages Alo(t+2); phi4 stages Ahi(t+2)+Bhi(t+2);
//   one counted wait per tile: vmcnt(6) [BM=256] / vmcnt(4) [BM=128] -> the
//   3 units for t+2 stay in flight across the boundary; every unit has >=3
//   phases (~600+ cyc) of load slack.  LDS XOR-swizzle via pre-swizzled global
//   source (linear global_load_lds dest) + swizzled ds_read; 0 bank conflicts.
// EPI: 0 = bf16 row-major, 1 = fp32 row-major, 2 = K-swizzled, 3 = V-swizzled.
template<int BM, int EPI, bool HAS_BIAS>
__global__ __launch_bounds__(512, 2) void gemm8p_kernel(
    const unsigned short* __restrict__ A, int lda,
    const unsigned short* __restrict__ BT,
    const float* __restrict__ bias, int nbias,
    void* __restrict__ Cout, int ldc, int K)
{
    constexpr int MR  = BM / 32;    // per-wave m fragment reps (4 or 8)
    constexpr int MH  = MR / 2;     // m reps per phase
    constexpr int ASZ = BM * 64;    // elements per A K-tile buffer
    __shared__ __align__(16) unsigned short lds[2 * ASZ + 32768];  // 96 or 128 KiB

    const int tid  = threadIdx.x;
    const int wave = tid >> 6, lane = tid & 63;
    const int wm = wave >> 2, wn = wave & 3;
    const int quad = lane >> 4, l15 = lane & 15;
    const int sw = l15 & 7;         // read-side XOR (== row&7 of every frag row)

    // T1: bijective XCD-aware swizzle of the linear workgroup id
    const int gx  = gridDim.x;
    const int nwg = gx * gridDim.y;
    int wg = blockIdx.y * gx + blockIdx.x;
    if (!(nwg & 7)) wg = (wg & 7) * (nwg >> 3) + (wg >> 3);
    const int bm = (wg / gx) * BM, bn = (wg % gx) * 256;

    const int nt = K >> 6;

    // staging: thread tid covers (row = tid/8, 16B-slot p = tid&7) of a
    // 64x64 unit; LDS dest linear => fetch pre-swizzled global column.
    const int srow = tid >> 3;
    const int scol = ((tid & 7) ^ (srow & 7)) << 3;  // elements
    const unsigned short* Ag = A  + (size_t)(bm + srow) * lda + scol;
    const unsigned short* Bg = BT + (size_t)(bn + srow) * K   + scol;
    unsigned short* const ldsA = &lds[wave * 512];
    unsigned short* const ldsB = &lds[2 * ASZ + wave * 512];

    // one 64-row stage unit = one global_load_lds sweep (512 thr x 16 B = 8 KB)
    auto stA64 = [&](int kt, int sub, int b) {
        gl_lds16(Ag + (size_t)(sub * 64) * lda + kt * 64, ldsA + b * ASZ + sub * 4096);
    };
    auto stB64 = [&](int kt, int sub, int b) {
        gl_lds16(Bg + (size_t)(sub * 64) * K + kt * 64, ldsB + b * 16384 + sub * 4096);
    };
    auto stAlo = [&](int kt, int b) { stA64(kt, 0, b); if constexpr (BM == 256) stA64(kt, 1, b); };
    auto stAhi = [&](int kt, int b) { if constexpr (BM == 256) { stA64(kt, 2, b); stA64(kt, 3, b); }
                                      else stA64(kt, 1, b); };
    auto stBlo = [&](int kt, int b) { stB64(kt, 0, b); stB64(kt, 1, b); };
    auto stBhi = [&](int kt, int b) { stB64(kt, 2, b); stB64(kt, 3, b); };

    // fragment reads: logical (row, slot s=ks*4+quad) -> physical slot s ^ (row&7)
    auto ldA = [&](int b, int m, int ks) -> bf16x8 {
        int ra = m * 32 + wm * 16 + l15;
        return *(const bf16x8*)&lds[b * ASZ + ra * 64 + (((ks * 4 + quad) ^ sw) << 3)];
    };
    auto ldB = [&](int b, int j, int ks) -> bf16x8 {
        int rb = j * 64 + wn * 16 + l15;
        return *(const bf16x8*)&lds[2 * ASZ + b * 16384 + rb * 64 + (((ks * 4 + quad) ^ sw) << 3)];
    };

    f32x4 acc[MR][4] = {};
    bf16x8 af[MH][2], bl[2][2], bh[2][2];

    // ---- prologue: tile0 fully; then Alo(1), Ahi(1), Bhi(1) stay in flight ----
    stAlo(0, 0); stAhi(0, 0); stBlo(0, 0); stBhi(0, 0);
    if (nt > 1) {
        stAlo(1, 1);
        stAhi(1, 1); stBhi(1, 1);
        if constexpr (BM == 256) { VMCNT(6); } else { VMCNT(4); }
    } else {
        VMCNT(0);
    }
    __builtin_amdgcn_s_barrier();
    MEMFENCE();

    for (int t = 0; t < nt; ++t) {
        const int b = t & 1, nb = b ^ 1;
        const bool s1 = (t + 1 < nt), s2 = (t + 2 < nt);

        // ---------- phi1: A-lo + B-lo frags; stage Blo(t+1) ----------
#pragma unroll
        for (int m = 0; m < MH; ++m)
#pragma unroll
            for (int ks = 0; ks < 2; ++ks) af[m][ks] = ldA(b, m, ks);
#pragma unroll
        for (int j = 0; j < 2; ++j)
#pragma unroll
            for (int ks = 0; ks < 2; ++ks) bl[j][ks] = ldB(b, j, ks);
        if (s1) stBlo(t + 1, nb);
        __builtin_amdgcn_s_barrier();
        LGKM0();
        __builtin_amdgcn_sched_barrier(0);
        __builtin_amdgcn_s_setprio(1);
#pragma unroll
        for (int m = 0; m < MH; ++m)
#pragma unroll
            for (int j = 0; j < 2; ++j)
#pragma unroll
                for (int ks = 0; ks < 2; ++ks)
                    acc[m][j] = __builtin_amdgcn_mfma_f32_16x16x32_bf16(af[m][ks], bl[j][ks], acc[m][j], 0, 0, 0);
        __builtin_amdgcn_s_setprio(0);
        __builtin_amdgcn_s_barrier();

        // ---------- phi2: B-hi frags, reuse A-lo ----------
#pragma unroll
        for (int j = 0; j < 2; ++j)
#pragma unroll
            for (int ks = 0; ks < 2; ++ks) bh[j][ks] = ldB(b, 2 + j, ks);
        __builtin_amdgcn_s_barrier();
        LGKM0();
        __builtin_amdgcn_sched_barrier(0);
        __builtin_amdgcn_s_setprio(1);
#pragma unroll
        for (int m = 0; m < MH; ++m)
#pragma unroll
            for (int j = 0; j < 2; ++j)
#pragma unroll
                for (int ks = 0; ks < 2; ++ks)
                    acc[m][2 + j] = __builtin_amdgcn_mfma_f32_16x16x32_bf16(af[m][ks], bh[j][ks], acc[m][2 + j], 0, 0, 0);
        __builtin_amdgcn_s_setprio(0);
        __builtin_amdgcn_s_barrier();

        // ---------- phi3: A-hi frags, reuse B-hi; stage Alo(t+2) ----------
#pragma unroll
        for (int m = 0; m < MH; ++m)
#pragma unroll
            for (int ks = 0; ks < 2; ++ks) af[m][ks] = ldA(b, MH + m, ks);
        if (s2) stAlo(t + 2, b);
        __builtin_amdgcn_s_barrier();
        LGKM0();
        __builtin_amdgcn_sched_barrier(0);
        __builtin_amdgcn_s_setprio(1);
#pragma unroll
        for (int m = 0; m < MH; ++m)
#pragma unroll
            for (int j = 0; j < 2; ++j)
#pragma unroll
                for (int ks = 0; ks < 2; ++ks)
                    acc[MH + m][2 + j] = __builtin_amdgcn_mfma_f32_16x16x32_bf16(af[m][ks], bh[j][ks], acc[MH + m][2 + j], 0, 0, 0);
        __builtin_amdgcn_s_setprio(0);
        __builtin_amdgcn_s_barrier();

        // ---------- phi4: B-lo reload, reuse A-hi; stage Ahi(t+2)+Bhi(t+2) ----------
#pragma unroll
        for (int j = 0; j < 2; ++j)
#pragma unroll
            for (int ks = 0; ks < 2; ++ks) bl[j][ks] = ldB(b, j, ks);
        if (s2) { stAhi(t + 2, b); stBhi(t + 2, b); }
        __builtin_amdgcn_s_barrier();
        LGKM0();
        __builtin_amdgcn_sched_barrier(0);
        __builtin_amdgcn_s_setprio(1);
#pragma unroll
        for (int m = 0; m < MH; ++m)
#pragma unroll
            for (int j = 0; j < 2; ++j)
#pragma unroll
                for (int ks = 0; ks < 2; ++ks)
                    acc[MH + m][j] = __builtin_amdgcn_mfma_f32_16x16x32_bf16(af[m][ks], bl[j][ks], acc[MH + m][j], 0, 0, 0);
        __builtin_amdgcn_s_setprio(0);
        // tile boundary: t+1's 4 units drained; t+2's 3 staged units stay in flight
        if (s2) { if constexpr (BM == 256) { VMCNT(6); } else { VMCNT(4); } }
        else    { VMCNT(0); }
        __builtin_amdgcn_s_barrier();
        MEMFENCE();  // no LDS read may hoist above this tile boundary
    }

    // ---------- epilogue (interleaved mapping) ----------
#pragma unroll
    for (int m = 0; m < MR; ++m)
#pragma unroll
        for (int j = 0; j < 4; ++j)
#pragma unroll
            for (int r = 0; r < 4; ++r) {
                int row = bm + m * 32 + wm * 16 + quad * 4 + r;
                int col = bn + j * 64 + wn * 16 + l15;
                float val = acc[m][j][r];
                if (HAS_BIAS && col < nbias) val += bias[col];
                if (EPI == 2) {
                    // K frag layout, head bh=b*16+h: [tile s/64][dim-chunk d/8][key s%64][d%8]
                    int bb = row >> 11, s = row & 2047, hh = col >> 7, d = col & 127;
                    size_t idx = ((size_t)((bb << 4) + hh) << 18) + ((size_t)(s >> 6) << 13)
                               + ((d >> 3) << 9) + ((s & 63) << 3) + (d & 7);
                    ((unsigned short*)Cout)[idx] = f2bf(val);
                } else if (EPI == 3) {
                    // V frag layout, head bh: [tile s/64][key-chunk (s%64)/8][dim d(128)][s%8]
                    int bb = row >> 11, s = row & 2047, hh = col >> 7, d = col & 127;
                    size_t idx = ((size_t)((bb << 4) + hh) << 18) + ((size_t)(s >> 6) << 13)
                               + (((s >> 3) & 7) << 10) + (d << 3) + (s & 7);
                    ((unsigned short*)Cout)[idx] = f2bf(val);
                } else if (EPI == 1) {
                    ((float*)Cout)[(size_t)row * ldc + col] = val;
                } else {
                    ((unsigned short*)Cout)[(size_t)row * ldc + col] = f2bf(val);
                }
            }
}

// ---------------- MFMA flash attention: fixed-offset softmax, MFMA row-sum ----------------
// grid 1024 blocks (32 bh x 32 q-tiles of 64), 256 threads (4 waves x 16 queries).
__global__ __launch_bounds__(256) void flash_attn_mfma_kernel(
    const unsigned short* __restrict__ q,
    const unsigned short* __restrict__ kswz,
    const unsigned short* __restrict__ vswz,
    unsigned short* __restrict__ o)
{
    __shared__ __align__(16) unsigned short Kl[2][8192];    // 32 KB dbuf [chunk16][key64][8]
    __shared__ __align__(16) unsigned short Vl[8192];       // 16 KB [chunk8][dim128][8]
    __shared__ __align__(16) unsigned short Ps[4][16][72];  // wave-private P

    const int tid  = threadIdx.x;
    const int wave = tid >> 6;
    const int lane = tid & 63;
    const int quad = lane >> 4, l15 = lane & 15;

    const int bid = blockIdx.x;
    const int qt = 31 - (bid >> 5);     // longest tiles dispatch first
    const int bh = bid & 31;            // head pinned to one XCD-L2
    const int b  = bh >> 4, h = bh & 15;
    const int q0 = qt * 64;

    const unsigned short* qbase = q + (size_t)(b * PS + q0) * PNCAT + h * PHD;
    const unsigned short* kbase = kswz + ((size_t)bh << 18);
    const unsigned short* vbase = vswz + ((size_t)bh << 18);

    auto stageK = [&](int it, int buf) {
        const unsigned short* kt = kbase + ((size_t)it << 13);
#pragma unroll
        for (int j = 0; j < 4; ++j)
            gl_lds16(kt + (wave * 4 + j) * 512 + lane * 8, &Kl[buf][(wave * 4 + j) * 512]);
    };
    auto stageV = [&](int it) {
        const unsigned short* vt = vbase + ((size_t)it << 13);
#pragma unroll
        for (int j = 0; j < 4; ++j)
            gl_lds16(vt + (wave * 4 + j) * 512 + lane * 8, &Vl[(wave * 4 + j) * 512]);
    };

    // Q A-frags: registers for whole kernel
    bf16x8 aq[4];
#pragma unroll
    for (int kk = 0; kk < 4; ++kk)
        aq[kk] = *(const bf16x8*)(qbase + (size_t)(wave * 16 + l15) * PNCAT + kk * 32 + quad * 8);

    bf16x8 vones;
#pragma unroll
    for (int j = 0; j < 8; ++j) vones[j] = (short)0x3F80;

    f32x4 oacc[8] = {};
    f32x4 lacc = {};

    stageK(0, 0);   // prologue prefetch

    for (int it = 0; it <= qt; ++it) {
        const int cur = it & 1;
        __syncthreads();   // B1: K[it] visible; prior-iter Vl readers done
        stageV(it);
        if (it < qt) stageK(it + 1, cur ^ 1);

        // ---- S = Q K^T on Kl[cur] ----
        f32x4 sacc[4] = {};
#pragma unroll
        for (int kk = 0; kk < 4; ++kk)
#pragma unroll
            for (int n = 0; n < 4; ++n) {
                bf16x8 bk = *(const bf16x8*)&Kl[cur][((kk * 4 + quad) * 64 + n * 16 + l15) * 8];
                sacc[n] = __builtin_amdgcn_mfma_f32_16x16x32_bf16(aq[kk], bk, sacc[n], 0, 0, 0);
            }

        // ---- P = exp(s*scale - MOFF); causal zero on diagonal tile; write to LDS ----
        const bool diag = (it == qt);
#pragma unroll
        for (int n = 0; n < 4; ++n)
#pragma unroll
            for (int r = 0; r < 4; ++r) {
                float p = __expf(fmaf(sacc[n][r], ATT_SCALE, -ATT_MOFF));
                if (diag && (n * 16 + l15 > wave * 16 + quad * 4 + r)) p = 0.0f;
                Ps[wave][quad * 4 + r][n * 16 + l15] = f2bf(p);  // wave-private
            }

        __syncthreads();   // B2: V[it] visible (loads had QK+exp in flight)

        // ---- O += P V ; l += P 1 (row-sum via ones MFMA) ----
#pragma unroll
        for (int kk = 0; kk < 2; ++kk) {
            bf16x8 ap = *(const bf16x8*)&Ps[wave][l15][kk * 32 + quad * 8];
            lacc = __builtin_amdgcn_mfma_f32_16x16x32_bf16(ap, vones, lacc, 0, 0, 0);
#pragma unroll
            for (int n = 0; n < 8; ++n) {
                bf16x8 bv = *(const bf16x8*)&Vl[((kk * 4 + quad) * 128 + n * 16 + l15) * 8];
                oacc[n] = __builtin_amdgcn_mfma_f32_16x16x32_bf16(ap, bv, oacc[n], 0, 0, 0);
            }
        }
    }

    // ---- epilogue: normalize by l, store bf16 ----
    float inv[4];
#pragma unroll
    for (int r = 0; r < 4; ++r) inv[r] = 1.0f / lacc[r];
#pragma unroll
    for (int n = 0; n < 8; ++n)
#pragma unroll
        for (int r = 0; r < 4; ++r) {
            int row = q0 + wave * 16 + quad * 4 + r;
            int col = h * PHD + n * 16 + l15;
            o[(size_t)(b * PS + row) * PH + col] = f2bf(oacc[n][r] * inv[r]);
        }
}

// ---------------- host launcher ----------------
extern "C" void kernel_launch(void* const* d_in, const int* in_sizes, int n_in,
                              void* d_out, int out_size, void* d_ws, size_t ws_size,
                              hipStream_t stream)
{
    const float* x      = (const float*)d_in[0];
    const float* wq     = (const float*)d_in[1];
    const float* bq     = (const float*)d_in[2];
    const float* wk_lat = (const float*)d_in[3];
    const float* wv_lat = (const float*)d_in[4];
    const float* wk     = (const float*)d_in[5];
    const float* wv     = (const float*)d_in[6];
    const float* wo     = (const float*)d_in[7];
    const float* bo     = (const float*)d_in[8];
    float* out = (float*)d_out;

    char* ws = (char*)d_ws;
    size_t off = 0;
    auto alloc = [&](size_t bytes) -> void* {
        void* p = ws + off;
        off += (bytes + 255) & ~(size_t)255;
        return p;
    };
    unsigned short* xb    = (unsigned short*)alloc((size_t)PM * PH * 2);       // 16 MB
    unsigned short* wcatT = (unsigned short*)alloc((size_t)PNCAT * PH * 2);    // 12 MB
    unsigned short* wkT   = (unsigned short*)alloc((size_t)PH * PLD * 2);      // 2 MB
    unsigned short* wvT   = (unsigned short*)alloc((size_t)PH * PLD * 2);      // 2 MB
    unsigned short* woT   = (unsigned short*)alloc((size_t)PH * PH * 2);       // 8 MB
    unsigned short* cat   = (unsigned short*)alloc((size_t)PM * PNCAT * 2);    // 24 MB
    unsigned short* kswz  = (unsigned short*)alloc((size_t)PM * PH * 2);       // 16 MB
    unsigned short* attn  = (unsigned short*)alloc((size_t)PM * PH * 2);       // 16 MB
    // vswz aliases xb: xb dead after the merged down-proj reads it.
    unsigned short* vswz  = xb;

    unsigned short* wqT    = wcatT;                                  // rows 0..2047
    unsigned short* wkLatT = wcatT + (size_t)PH * PH;                // rows 2048..2559
    unsigned short* wvLatT = wcatT + (size_t)(PH + PLD) * PH;        // rows 2560..3071

    dim3 tb(32, 8);

    // 1. cast x -> bf16
    cast_f32_bf16_kernel<<<(PM * PH) / 4 / 256, 256, 0, stream>>>(x, xb, PM * PH);
    // 2. transpose weights -> bf16 B^T layouts
    transpose_cast_kernel<<<dim3(PH / 32,  PH / 32),  tb, 0, stream>>>(wq,     wqT,    PH,  PH);
    transpose_cast_kernel<<<dim3(PLD / 32, PH / 32),  tb, 0, stream>>>(wk_lat, wkLatT, PH,  PLD);
    transpose_cast_kernel<<<dim3(PLD / 32, PH / 32),  tb, 0, stream>>>(wv_lat, wvLatT, PH,  PLD);
    transpose_cast_kernel<<<dim3(PH / 32,  PLD / 32), tb, 0, stream>>>(wk,     wkT,    PLD, PH);
    transpose_cast_kernel<<<dim3(PH / 32,  PLD / 32), tb, 0, stream>>>(wv,     wvT,    PLD, PH);
    transpose_cast_kernel<<<dim3(PH / 32,  PH / 32),  tb, 0, stream>>>(wo,     woT,    PH,  PH);

    // 3. merged down-projection: cat[M][3072] = xb @ [wq | wk_lat | wv_lat] (+bq on first 2048)
    //    256x256 tile -> grid 12x16 = 192 WGs
    gemm8p_kernel<256, 0, true><<<dim3(PNCAT / 256, PM / 256), 512, 0, stream>>>(
        xb, PH, wcatT, bq, PH, cat, PNCAT, PH);

    // 4. up-projections straight into MFMA-fragment-swizzled K / V
    //    128x256 tile -> grid 8x32 = 256 WGs (100% of CUs)
    gemm8p_kernel<128, 2, false><<<dim3(PH / 256, PM / 128), 512, 0, stream>>>(
        cat + PH, PNCAT, wkT, nullptr, 0, kswz, 0, PLD);
    gemm8p_kernel<128, 3, false><<<dim3(PH / 256, PM / 128), 512, 0, stream>>>(
        cat + PH + PLD, PNCAT, wvT, nullptr, 0, vswz, 0, PLD);

    // 5. causal MFMA flash attention
    flash_attn_mfma_kernel<<<PB * PNH * (PS / 64), 256, 0, stream>>>(cat, kswz, vswz, attn);

    // 6. output projection (fp32 out + bo), 128x256 tile -> 256 WGs
    gemm8p_kernel<128, 1, true><<<dim3(PH / 256, PM / 128), 512, 0, stream>>>(
        attn, PH, woT, bo, PH, out, PH, PH);
}

// Round 3
// 342.421 us; speedup vs baseline: 1.1152x; 1.0296x over previous
//
#include <hip/hip_runtime.h>
#include <hip/hip_bf16.h>
#include <type_traits>

// ---------------- constants (problem shape) ----------------
// B=2, S=2048, H=2048, NH=16, LD=512, HD=128
#define PB   2
#define PS   2048
#define PH   2048
#define PNH  16
#define PLD  512
#define PHD  128
#define PM   (PB * PS)          // 4096 rows in all GEMMs
#define PNCAT 3072              // merged down-proj width: 2048 q + 512 klat + 512 vlat
#define ATT_SCALE 0.08838834764831845f  // 1/sqrt(128)
#define ATT_MOFF 4.0f

typedef __attribute__((ext_vector_type(8))) short bf16x8;
typedef __attribute__((ext_vector_type(4))) float f32x4;

__device__ __forceinline__ unsigned short f2bf(float f) {
    unsigned int u = __float_as_uint(f);
    u += 0x7FFFu + ((u >> 16) & 1u);   // RNE
    return (unsigned short)(u >> 16);
}

// async global->LDS, 16 B per lane; LDS dest = wave-uniform base + lane*16
__device__ __forceinline__ void gl_lds16(const unsigned short* g, unsigned short* l) {
    __builtin_amdgcn_global_load_lds(
        (const __attribute__((address_space(1))) unsigned int*)g,
        (__attribute__((address_space(3))) unsigned int*)l, 16, 0, 0);
}

#define VMCNT(n)   asm volatile("s_waitcnt vmcnt(" #n ")" ::: "memory")
#define LGKM0()    asm volatile("s_waitcnt lgkmcnt(0)" ::: "memory")
#define MEMFENCE() asm volatile("" ::: "memory")

using btru = std::integral_constant<bool, true>;
using bfls = std::integral_constant<bool, false>;
using ib0  = std::integral_constant<int, 0>;
using ib1  = std::integral_constant<int, 1>;

// ---------------- cast fp32 -> bf16 (elementwise, 4/thread) ----------------
__global__ __launch_bounds__(256) void cast_f32_bf16_kernel(
    const float* __restrict__ in, unsigned short* __restrict__ out, int n)
{
    int i = (blockIdx.x * 256 + threadIdx.x) * 4;
    if (i >= n) return;
    float4 f = *(const float4*)(in + i);
    unsigned int a = (unsigned int)f2bf(f.x) | ((unsigned int)f2bf(f.y) << 16);
    unsigned int b = (unsigned int)f2bf(f.z) | ((unsigned int)f2bf(f.w) << 16);
    *(uint2*)(out + i) = make_uint2(a, b);
}

// ---------------- transpose + cast: in fp32 [R][C] -> out bf16 [C][R] ----------------
__global__ __launch_bounds__(256) void transpose_cast_kernel(
    const float* __restrict__ in, unsigned short* __restrict__ out, int R, int C)
{
    __shared__ float tile[32][33];
    int tx = threadIdx.x, ty = threadIdx.y;
    int r0 = blockIdx.y * 32, c0 = blockIdx.x * 32;
#pragma unroll
    for (int i = 0; i < 32; i += 8)
        tile[ty + i][tx] = in[(size_t)(r0 + ty + i) * C + (c0 + tx)];
    __syncthreads();
#pragma unroll
    for (int i = 0; i < 32; i += 8)
        out[(size_t)(c0 + ty + i) * R + (r0 + tx)] = f2bf(tile[tx][ty + i]);
}

// ---------------- 8-phase 256-wide bf16 MFMA GEMM, static dbuf ----------------
// BM in {128,256}, BN fixed 256. 512 threads = 8 waves, interleaved mapping:
//   A row = m*32 + wm*16 + l15 ; B row = j*64 + wn*16 + l15
// K-loop pair-unrolled (2 K-tiles/iter) so the double-buffer index is
// COMPILE-TIME: every ds_read/LDS-dest address folds to base + 16-bit imm
// (R2's runtime `t&1` forced dynamic VALU addressing every access -> 13%
// VALUBusy on the barrier-locked critical path).  Tail 2 tiles peeled ->
// branchless hot loop.  Stage schedule per tile t (4 phases):
//   phi1 stages Blo(t+1); phi3 stages Alo(t+2); phi4 stages Ahi(t+2)+Bhi(t+2);
//   boundary wait vmcnt(6) [BM=256] / vmcnt(4) [BM=128] keeps t+2 in flight.
// LDS XOR-swizzle via pre-swizzled global source + swizzled ds_read (0 conflicts).
// EPI: 0 = bf16 row-major, 1 = fp32 row-major, 2 = K-swizzled, 3 = V-swizzled.
template<int BM, int EPI, bool HAS_BIAS>
__global__ __launch_bounds__(512, 2) void gemm8p_kernel(
    const unsigned short* __restrict__ A, int lda,
    const unsigned short* __restrict__ BT,
    const float* __restrict__ bias, int nbias,
    void* __restrict__ Cout, int ldc, int K)
{
    constexpr int MR  = BM / 32;    // per-wave m fragment reps (4 or 8)
    constexpr int MH  = MR / 2;     // m reps per phase
    constexpr int ASZ = BM * 64;    // elements per A K-tile buffer
    __shared__ __align__(16) unsigned short lds[2 * ASZ + 32768];  // 96 or 128 KiB

    const int tid  = threadIdx.x;
    const int wave = tid >> 6, lane = tid & 63;
    const int wm = wave >> 2, wn = wave & 3;
    const int quad = lane >> 4, l15 = lane & 15;
    const int sw = l15 & 7;         // read-side XOR (== row&7 of every frag row)

    // T1: bijective XCD-aware swizzle of the linear workgroup id
    const int gx  = gridDim.x;
    const int nwg = gx * gridDim.y;
    int wg = blockIdx.y * gx + blockIdx.x;
    if (!(nwg & 7)) wg = (wg & 7) * (nwg >> 3) + (wg >> 3);
    const int bm = (wg / gx) * BM, bn = (wg % gx) * 256;

    const int nt = K >> 6;          // even, >= 4 for all our shapes

    // staging: thread tid covers (row = tid/8, 16B-slot p = tid&7) of a
    // 64x64 unit; LDS dest linear => fetch pre-swizzled global column.
    const int srow = tid >> 3;
    const int scol = ((tid & 7) ^ (srow & 7)) << 3;  // elements
    const unsigned short* Ag = A  + (size_t)(bm + srow) * lda + scol;
    const unsigned short* Bg = BT + (size_t)(bn + srow) * K   + scol;
    unsigned short* const ldsA = &lds[wave * 512];
    unsigned short* const ldsB = &lds[2 * ASZ + wave * 512];

    // one 64-row stage unit = one global_load_lds per wave (512 thr x 16 B = 8 KB)
    auto stA64 = [&](int kt, int sub, int b) {
        gl_lds16(Ag + (size_t)(sub * 64) * lda + kt * 64, ldsA + b * ASZ + sub * 4096);
    };
    auto stB64 = [&](int kt, int sub, int b) {
        gl_lds16(Bg + (size_t)(sub * 64) * K + kt * 64, ldsB + b * 16384 + sub * 4096);
    };
    auto stAlo = [&](int kt, int b) { stA64(kt, 0, b); if constexpr (BM == 256) stA64(kt, 1, b); };
    auto stAhi = [&](int kt, int b) { if constexpr (BM == 256) { stA64(kt, 2, b); stA64(kt, 3, b); }
                                      else stA64(kt, 1, b); };
    auto stBlo = [&](int kt, int b) { stB64(kt, 0, b); stB64(kt, 1, b); };
    auto stBhi = [&](int kt, int b) { stB64(kt, 2, b); stB64(kt, 3, b); };

    // fragment reads: logical (row, slot s=ks*4+quad) -> physical slot s ^ (row&7)
    auto ldA = [&](int b, int m, int ks) -> bf16x8 {
        int ra = m * 32 + wm * 16 + l15;
        return *(const bf16x8*)&lds[b * ASZ + ra * 64 + (((ks * 4 + quad) ^ sw) << 3)];
    };
    auto ldB = [&](int b, int j, int ks) -> bf16x8 {
        int rb = j * 64 + wn * 16 + l15;
        return *(const bf16x8*)&lds[2 * ASZ + b * 16384 + rb * 64 + (((ks * 4 + quad) ^ sw) << 3)];
    };

    f32x4 acc[MR][4] = {};

    // ---- one K-tile: 4 phases, compile-time buffer + stage flags ----
    auto tile = [&](auto bc, auto s1c, auto s2c, int t) {
        constexpr int  b  = decltype(bc)::value;
        constexpr int  nb = b ^ 1;
        constexpr bool s1 = decltype(s1c)::value;
        constexpr bool s2 = decltype(s2c)::value;
        bf16x8 af[MH][2], bfr[2][2];

        // ---------- phi1: A-lo + B-lo frags; stage Blo(t+1) ----------
#pragma unroll
        for (int m = 0; m < MH; ++m)
#pragma unroll
            for (int ks = 0; ks < 2; ++ks) af[m][ks] = ldA(b, m, ks);
#pragma unroll
        for (int j = 0; j < 2; ++j)
#pragma unroll
            for (int ks = 0; ks < 2; ++ks) bfr[j][ks] = ldB(b, j, ks);
        if constexpr (s1) stBlo(t + 1, nb);
        __builtin_amdgcn_s_barrier();
        LGKM0();
        __builtin_amdgcn_sched_barrier(0);
        __builtin_amdgcn_s_setprio(1);
#pragma unroll
        for (int m = 0; m < MH; ++m)
#pragma unroll
            for (int j = 0; j < 2; ++j)
#pragma unroll
                for (int ks = 0; ks < 2; ++ks)
                    acc[m][j] = __builtin_amdgcn_mfma_f32_16x16x32_bf16(af[m][ks], bfr[j][ks], acc[m][j], 0, 0, 0);
        __builtin_amdgcn_s_setprio(0);
        __builtin_amdgcn_s_barrier();

        // ---------- phi2: B-hi frags, reuse A-lo ----------
#pragma unroll
        for (int j = 0; j < 2; ++j)
#pragma unroll
            for (int ks = 0; ks < 2; ++ks) bfr[j][ks] = ldB(b, 2 + j, ks);
        __builtin_amdgcn_s_barrier();
        LGKM0();
        __builtin_amdgcn_sched_barrier(0);
        __builtin_amdgcn_s_setprio(1);
#pragma unroll
        for (int m = 0; m < MH; ++m)
#pragma unroll
            for (int j = 0; j < 2; ++j)
#pragma unroll
                for (int ks = 0; ks < 2; ++ks)
                    acc[m][2 + j] = __builtin_amdgcn_mfma_f32_16x16x32_bf16(af[m][ks], bfr[j][ks], acc[m][2 + j], 0, 0, 0);
        __builtin_amdgcn_s_setprio(0);
        __builtin_amdgcn_s_barrier();

        // ---------- phi3: A-hi frags, reuse B-hi; stage Alo(t+2) ----------
#pragma unroll
        for (int m = 0; m < MH; ++m)
#pragma unroll
            for (int ks = 0; ks < 2; ++ks) af[m][ks] = ldA(b, MH + m, ks);
        if constexpr (s2) stAlo(t + 2, b);
        __builtin_amdgcn_s_barrier();
        LGKM0();
        __builtin_amdgcn_sched_barrier(0);
        __builtin_amdgcn_s_setprio(1);
#pragma unroll
        for (int m = 0; m < MH; ++m)
#pragma unroll
            for (int j = 0; j < 2; ++j)
#pragma unroll
                for (int ks = 0; ks < 2; ++ks)
                    acc[MH + m][2 + j] = __builtin_amdgcn_mfma_f32_16x16x32_bf16(af[m][ks], bfr[j][ks], acc[MH + m][2 + j], 0, 0, 0);
        __builtin_amdgcn_s_setprio(0);
        __builtin_amdgcn_s_barrier();

        // ---------- phi4: B-lo reload, reuse A-hi; stage Ahi(t+2)+Bhi(t+2) ----------
#pragma unroll
        for (int j = 0; j < 2; ++j)
#pragma unroll
            for (int ks = 0; ks < 2; ++ks) bfr[j][ks] = ldB(b, j, ks);
        if constexpr (s2) { stAhi(t + 2, b); stBhi(t + 2, b); }
        __builtin_amdgcn_s_barrier();
        LGKM0();
        __builtin_amdgcn_sched_barrier(0);
        __builtin_amdgcn_s_setprio(1);
#pragma unroll
        for (int m = 0; m < MH; ++m)
#pragma unroll
            for (int j = 0; j < 2; ++j)
#pragma unroll
                for (int ks = 0; ks < 2; ++ks)
                    acc[MH + m][j] = __builtin_amdgcn_mfma_f32_16x16x32_bf16(af[m][ks], bfr[j][ks], acc[MH + m][j], 0, 0, 0);
        __builtin_amdgcn_s_setprio(0);
        // tile boundary: t+1's 4 units drained; t+2's 3 staged units stay in flight
        if constexpr (s2) { if constexpr (BM == 256) { VMCNT(6); } else { VMCNT(4); } }
        else              { VMCNT(0); }
        __builtin_amdgcn_s_barrier();
        MEMFENCE();  // no LDS read may hoist above this tile boundary
    };

    // ---- prologue: tile0 fully; then Alo(1), Ahi(1), Bhi(1) stay in flight ----
    stAlo(0, 0); stAhi(0, 0); stBlo(0, 0); stBhi(0, 0);
    stAlo(1, 1); stAhi(1, 1); stBhi(1, 1);
    if constexpr (BM == 256) { VMCNT(6); } else { VMCNT(4); }
    __builtin_amdgcn_s_barrier();
    MEMFENCE();

    // ---- main loop: pairs of K-tiles, static buffers, branchless ----
    int t = 0;
    for (; t + 3 < nt; t += 2) {
        tile(ib0{}, btru{}, btru{}, t);
        tile(ib1{}, btru{}, btru{}, t + 1);
    }
    // ---- peeled tail: tiles nt-2 (stages Blo(nt-1), drains) and nt-1 ----
    tile(ib0{}, btru{}, bfls{}, nt - 2);
    tile(ib1{}, bfls{}, bfls{}, nt - 1);

    // ---------- epilogue (interleaved mapping) ----------
#pragma unroll
    for (int m = 0; m < MR; ++m)
#pragma unroll
        for (int j = 0; j < 4; ++j)
#pragma unroll
            for (int r = 0; r < 4; ++r) {
                int row = bm + m * 32 + wm * 16 + quad * 4 + r;
                int col = bn + j * 64 + wn * 16 + l15;
                float val = acc[m][j][r];
                if (HAS_BIAS && col < nbias) val += bias[col];
                if (EPI == 2) {
                    // K frag layout, head bh=b*16+h: [tile s/64][dim-chunk d/8][key s%64][d%8]
                    int bb = row >> 11, s = row & 2047, hh = col >> 7, d = col & 127;
                    size_t idx = ((size_t)((bb << 4) + hh) << 18) + ((size_t)(s >> 6) << 13)
                               + ((d >> 3) << 9) + ((s & 63) << 3) + (d & 7);
                    ((unsigned short*)Cout)[idx] = f2bf(val);
                } else if (EPI == 3) {
                    // V frag layout, head bh: [tile s/64][key-chunk (s%64)/8][dim d(128)][s%8]
                    int bb = row >> 11, s = row & 2047, hh = col >> 7, d = col & 127;
                    size_t idx = ((size_t)((bb << 4) + hh) << 18) + ((size_t)(s >> 6) << 13)
                               + (((s >> 3) & 7) << 10) + (d << 3) + (s & 7);
                    ((unsigned short*)Cout)[idx] = f2bf(val);
                } else if (EPI == 1) {
                    ((float*)Cout)[(size_t)row * ldc + col] = val;
                } else {
                    ((unsigned short*)Cout)[(size_t)row * ldc + col] = f2bf(val);
                }
            }
}

// ---------------- MFMA flash attention: fixed-offset softmax, MFMA row-sum ----------------
// grid 1024 blocks (32 bh x 32 q-tiles of 64), 256 threads (4 waves x 16 queries).
__global__ __launch_bounds__(256) void flash_attn_mfma_kernel(
    const unsigned short* __restrict__ q,
    const unsigned short* __restrict__ kswz,
    const unsigned short* __restrict__ vswz,
    unsigned short* __restrict__ o)
{
    __shared__ __align__(16) unsigned short Kl[2][8192];    // 32 KB dbuf [chunk16][key64][8]
    __shared__ __align__(16) unsigned short Vl[8192];       // 16 KB [chunk8][dim128][8]
    __shared__ __align__(16) unsigned short Ps[4][16][72];  // wave-private P

    const int tid  = threadIdx.x;
    const int wave = tid >> 6;
    const int lane = tid & 63;
    const int quad = lane >> 4, l15 = lane & 15;

    const int bid = blockIdx.x;
    const int qt = 31 - (bid >> 5);     // longest tiles dispatch first
    const int bh = bid & 31;            // head pinned to one XCD-L2
    const int b  = bh >> 4, h = bh & 15;
    const int q0 = qt * 64;

    const unsigned short* qbase = q + (size_t)(b * PS + q0) * PNCAT + h * PHD;
    const unsigned short* kbase = kswz + ((size_t)bh << 18);
    const unsigned short* vbase = vswz + ((size_t)bh << 18);

    auto stageK = [&](int it, int buf) {
        const unsigned short* kt = kbase + ((size_t)it << 13);
#pragma unroll
        for (int j = 0; j < 4; ++j)
            gl_lds16(kt + (wave * 4 + j) * 512 + lane * 8, &Kl[buf][(wave * 4 + j) * 512]);
    };
    auto stageV = [&](int it) {
        const unsigned short* vt = vbase + ((size_t)it << 13);
#pragma unroll
        for (int j = 0; j < 4; ++j)
            gl_lds16(vt + (wave * 4 + j) * 512 + lane * 8, &Vl[(wave * 4 + j) * 512]);
    };

    // Q A-frags: registers for whole kernel
    bf16x8 aq[4];
#pragma unroll
    for (int kk = 0; kk < 4; ++kk)
        aq[kk] = *(const bf16x8*)(qbase + (size_t)(wave * 16 + l15) * PNCAT + kk * 32 + quad * 8);

    bf16x8 vones;
#pragma unroll
    for (int j = 0; j < 8; ++j) vones[j] = (short)0x3F80;

    f32x4 oacc[8] = {};
    f32x4 lacc = {};

    stageK(0, 0);   // prologue prefetch

    for (int it = 0; it <= qt; ++it) {
        const int cur = it & 1;
        __syncthreads();   // B1: K[it] visible; prior-iter Vl readers done
        stageV(it);
        if (it < qt) stageK(it + 1, cur ^ 1);

        // ---- S = Q K^T on Kl[cur] ----
        f32x4 sacc[4] = {};
#pragma unroll
        for (int kk = 0; kk < 4; ++kk)
#pragma unroll
            for (int n = 0; n < 4; ++n) {
                bf16x8 bk = *(const bf16x8*)&Kl[cur][((kk * 4 + quad) * 64 + n * 16 + l15) * 8];
                sacc[n] = __builtin_amdgcn_mfma_f32_16x16x32_bf16(aq[kk], bk, sacc[n], 0, 0, 0);
            }

        // ---- P = exp(s*scale - MOFF); causal zero on diagonal tile; write to LDS ----
        const bool diag = (it == qt);
#pragma unroll
        for (int n = 0; n < 4; ++n)
#pragma unroll
            for (int r = 0; r < 4; ++r) {
                float p = __expf(fmaf(sacc[n][r], ATT_SCALE, -ATT_MOFF));
                if (diag && (n * 16 + l15 > wave * 16 + quad * 4 + r)) p = 0.0f;
                Ps[wave][quad * 4 + r][n * 16 + l15] = f2bf(p);  // wave-private
            }

        __syncthreads();   // B2: V[it] visible (loads had QK+exp in flight)

        // ---- O += P V ; l += P 1 (row-sum via ones MFMA) ----
#pragma unroll
        for (int kk = 0; kk < 2; ++kk) {
            bf16x8 ap = *(const bf16x8*)&Ps[wave][l15][kk * 32 + quad * 8];
            lacc = __builtin_amdgcn_mfma_f32_16x16x32_bf16(ap, vones, lacc, 0, 0, 0);
#pragma unroll
            for (int n = 0; n < 8; ++n) {
                bf16x8 bv = *(const bf16x8*)&Vl[((kk * 4 + quad) * 128 + n * 16 + l15) * 8];
                oacc[n] = __builtin_amdgcn_mfma_f32_16x16x32_bf16(ap, bv, oacc[n], 0, 0, 0);
            }
        }
    }

    // ---- epilogue: normalize by l, store bf16 ----
    float inv[4];
#pragma unroll
    for (int r = 0; r < 4; ++r) inv[r] = 1.0f / lacc[r];
#pragma unroll
    for (int n = 0; n < 8; ++n)
#pragma unroll
        for (int r = 0; r < 4; ++r) {
            int row = q0 + wave * 16 + quad * 4 + r;
            int col = h * PHD + n * 16 + l15;
            o[(size_t)(b * PS + row) * PH + col] = f2bf(oacc[n][r] * inv[r]);
        }
}

// ---------------- host launcher ----------------
extern "C" void kernel_launch(void* const* d_in, const int* in_sizes, int n_in,
                              void* d_out, int out_size, void* d_ws, size_t ws_size,
                              hipStream_t stream)
{
    const float* x      = (const float*)d_in[0];
    const float* wq     = (const float*)d_in[1];
    const float* bq     = (const float*)d_in[2];
    const float* wk_lat = (const float*)d_in[3];
    const float* wv_lat = (const float*)d_in[4];
    const float* wk     = (const float*)d_in[5];
    const float* wv     = (const float*)d_in[6];
    const float* wo     = (const float*)d_in[7];
    const float* bo     = (const float*)d_in[8];
    float* out = (float*)d_out;

    char* ws = (char*)d_ws;
    size_t off = 0;
    auto alloc = [&](size_t bytes) -> void* {
        void* p = ws + off;
        off += (bytes + 255) & ~(size_t)255;
        return p;
    };
    unsigned short* xb    = (unsigned short*)alloc((size_t)PM * PH * 2);       // 16 MB
    unsigned short* wcatT = (unsigned short*)alloc((size_t)PNCAT * PH * 2);    // 12 MB
    unsigned short* wkT   = (unsigned short*)alloc((size_t)PH * PLD * 2);      // 2 MB
    unsigned short* wvT   = (unsigned short*)alloc((size_t)PH * PLD * 2);      // 2 MB
    unsigned short* woT   = (unsigned short*)alloc((size_t)PH * PH * 2);       // 8 MB
    unsigned short* cat   = (unsigned short*)alloc((size_t)PM * PNCAT * 2);    // 24 MB
    unsigned short* kswz  = (unsigned short*)alloc((size_t)PM * PH * 2);       // 16 MB
    unsigned short* attn  = (unsigned short*)alloc((size_t)PM * PH * 2);       // 16 MB
    // vswz aliases xb: xb dead after the merged down-proj reads it.
    unsigned short* vswz  = xb;

    unsigned short* wqT    = wcatT;                                  // rows 0..2047
    unsigned short* wkLatT = wcatT + (size_t)PH * PH;                // rows 2048..2559
    unsigned short* wvLatT = wcatT + (size_t)(PH + PLD) * PH;        // rows 2560..3071

    dim3 tb(32, 8);

    // 1. cast x -> bf16
    cast_f32_bf16_kernel<<<(PM * PH) / 4 / 256, 256, 0, stream>>>(x, xb, PM * PH);
    // 2. transpose weights -> bf16 B^T layouts
    transpose_cast_kernel<<<dim3(PH / 32,  PH / 32),  tb, 0, stream>>>(wq,     wqT,    PH,  PH);
    transpose_cast_kernel<<<dim3(PLD / 32, PH / 32),  tb, 0, stream>>>(wk_lat, wkLatT, PH,  PLD);
    transpose_cast_kernel<<<dim3(PLD / 32, PH / 32),  tb, 0, stream>>>(wv_lat, wvLatT, PH,  PLD);
    transpose_cast_kernel<<<dim3(PH / 32,  PLD / 32), tb, 0, stream>>>(wk,     wkT,    PLD, PH);
    transpose_cast_kernel<<<dim3(PH / 32,  PLD / 32), tb, 0, stream>>>(wv,     wvT,    PLD, PH);
    transpose_cast_kernel<<<dim3(PH / 32,  PH / 32),  tb, 0, stream>>>(wo,     woT,    PH,  PH);

    // 3. merged down-projection: cat[M][3072] = xb @ [wq | wk_lat | wv_lat] (+bq on first 2048)
    //    256x256 tile -> grid 12x16 = 192 WGs
    gemm8p_kernel<256, 0, true><<<dim3(PNCAT / 256, PM / 256), 512, 0, stream>>>(
        xb, PH, wcatT, bq, PH, cat, PNCAT, PH);

    // 4. up-projections straight into MFMA-fragment-swizzled K / V
    //    128x256 tile -> grid 8x32 = 256 WGs (100% of CUs)
    gemm8p_kernel<128, 2, false><<<dim3(PH / 256, PM / 128), 512, 0, stream>>>(
        cat + PH, PNCAT, wkT, nullptr, 0, kswz, 0, PLD);
    gemm8p_kernel<128, 3, false><<<dim3(PH / 256, PM / 128), 512, 0, stream>>>(
        cat + PH + PLD, PNCAT, wvT, nullptr, 0, vswz, 0, PLD);

    // 5. causal MFMA flash attention
    flash_attn_mfma_kernel<<<PB * PNH * (PS / 64), 256, 0, stream>>>(cat, kswz, vswz, attn);

    // 6. output projection (fp32 out + bo), 128x256 tile -> 256 WGs
    gemm8p_kernel<128, 1, true><<<dim3(PH / 256, PM / 128), 512, 0, stream>>>(
        attn, PH, woT, bo, PH, out, PH, PH);
}